// Round 4
// baseline (595.509 us; speedup 1.0000x reference)
//
#include <hip/hip_runtime.h>
#include <stdint.h>
#include <stddef.h>

// B=4,N=64 -> BN=256 batches; L=256; IN=128; H=512; heads=8; hd=64.
// Inputs may be bf16 OR float32 (harness-dependent) -> runtime-detected flag.
// All internal compute: bf16 MFMA + fp32 accumulate.

typedef __attribute__((ext_vector_type(8))) short short8;
typedef __attribute__((ext_vector_type(4))) float f32x4;

#define AS1(p) ((const __attribute__((address_space(1))) void*)(p))
#define AS3(p) ((__attribute__((address_space(3))) void*)(p))

__device__ __forceinline__ float b2f(uint16_t u) {
    union { uint32_t i; float f; } x; x.i = ((uint32_t)u) << 16; return x.f;
}
__device__ __forceinline__ uint16_t f2b(float f) {
    union { float f; uint32_t i; } x; x.f = f;
    uint32_t r = x.i + 0x7fffu + ((x.i >> 16) & 1u);  // RNE
    return (uint16_t)(r >> 16);
}

// ---------------------------------------------------------------------------
// Dtype sniffer: bf16 N(0,1) data -> exponent field in ~[110,135] (outliers
// ~0%). float32 data read as uint16: even elements are f32 low-mantissa
// halves -> ~uniform exponent bits -> ~42% outliers. flag=1 means float32.
// ---------------------------------------------------------------------------
__global__ void k_detect(const uint16_t* __restrict__ q, int* __restrict__ flag) {
    const int t = threadIdx.x;
    int cnt = 0;
    for (int i = 0; i < 32; ++i) {
        const int e = (q[t * 32 + i] >> 7) & 0xff;
        cnt += (e < 110) | (e > 135);
    }
#pragma unroll
    for (int m = 1; m < 64; m <<= 1) cnt += __shfl_xor(cnt, m, 64);
    if (t == 0) *flag = (cnt > 256) ? 1 : 0;
}

__device__ __forceinline__ uint16_t rd_any(const void* p, size_t idx, int isf) {
    return isf ? f2b(((const float*)p)[idx]) : ((const uint16_t*)p)[idx];
}

// ---------------------------------------------------------------------------
// Transpose weights W (K x 512) -> Wt (512 x K) bf16, so GEMM B-fragments
// read 16B contiguous along k. Tiny, L2-resident.
// ---------------------------------------------------------------------------
__global__ void k_transpose(const void* __restrict__ Wq, const void* __restrict__ Wk,
                            const void* __restrict__ Wv, const void* __restrict__ Wo,
                            uint16_t* __restrict__ wtq, uint16_t* __restrict__ wtk,
                            uint16_t* __restrict__ wtv, uint16_t* __restrict__ wto,
                            const int* __restrict__ flag) {
    const int isf = *flag;
    const int z = blockIdx.y;
    const int t = blockIdx.x * 256 + threadIdx.x;
    if (z < 3) {
        if (t >= 128 * 512) return;
        const void* W = (z == 0) ? Wq : (z == 1) ? Wk : Wv;
        uint16_t* o = (z == 0) ? wtq : (z == 1) ? wtk : wtv;
        const int k = t & 127, n = t >> 7;
        o[t] = rd_any(W, (size_t)k * 512 + n, isf);   // o[n*128+k] = W[k][n]
    } else {
        const int k = t & 511, n = t >> 9;
        wto[t] = rd_any(Wo, (size_t)k * 512 + n, isf);
    }
}

// ---------------------------------------------------------------------------
// GEMM v3: C(M x 512) = A(M x K) @ Wt(512 x K)^T + bias. 128x128 tile, BK=64,
// 4 waves 2x2, 16x16x32 bf16 MFMA, chunk-XOR LDS swizzle.
//
// Pipeline (T14, register prefetch, SINGLE 32 KB LDS buffer -- round-2's
// LDS double-buffer halved occupancy and regressed):
//   prologue: load tile0 -> regs; ds_write; sync
//   iter kt:  issue tile kt+1 global loads -> regs   (flies under MFMA)
//             compute MFMA on LDS tile kt
//             sync; ds_write regs (f32 converts HERE, not at load, so no
//             waitcnt lands before compute); sync
// Staging latency hides under compute; LDS stays 32 KB; exposed cost per
// K-step is just 2 barriers + 8 ds_write_b128.
//
// Grid: n-tile on blockIdx.x (FAST axis) so the 4 blocks sharing one A-tile
// are dispatched back-to-back -> A fetched from HBM once, 3 L2/L3 hits
// (was: m fastest, 4x logical A re-read, FETCH 188 vs 108 MB ideal).
// ---------------------------------------------------------------------------
template<int KITERS>
__device__ __forceinline__ void gemm_dev(const void* __restrict__ Av, const int lda,
                                         const uint16_t* __restrict__ Wt,
                                         const void* __restrict__ biasv,
                                         void* __restrict__ Cv,
                                         const int isf_a, const int isf_bias, const int isf_c) {
    __shared__ __align__(16) uint16_t At[128 * 64];
    __shared__ __align__(16) uint16_t Bt[128 * 64];
    const int n0 = blockIdx.x * 128, m0 = blockIdx.y * 128;  // n = fast axis
    const int tid = threadIdx.x;
    const int lane = tid & 63, w = tid >> 6;
    const int wr = w >> 1, wc = w & 1;
    const int quad = lane >> 4, cl = lane & 15;

    f32x4 acc[4][4];
#pragma unroll
    for (int i = 0; i < 4; ++i)
#pragma unroll
        for (int j = 0; j < 4; ++j) acc[i][j] = (f32x4){0.f, 0.f, 0.f, 0.f};

    short8 wreg[4];   // W prefetch (bf16)
    short8 areg[4];   // A prefetch (bf16 path)
    f32x4 ar[8];      // A prefetch (f32 path; convert deferred to ds_write)

    // ---- prologue: tile 0 -> regs -> LDS ----
#pragma unroll
    for (int i = 0; i < 4; ++i) {
        const int s = i * 256 + tid;
        const int row = s >> 3;
        const int gc = (s & 7) ^ (row & 7);
        wreg[i] = *(const short8*)(Wt + (size_t)(n0 + row) * lda + gc * 8);
        if (!isf_a) {
            areg[i] = *(const short8*)((const uint16_t*)Av + (size_t)(m0 + row) * lda + gc * 8);
        } else {
            const float* p = (const float*)Av + (size_t)(m0 + row) * lda + gc * 8;
            ar[2 * i] = *(const f32x4*)p;
            ar[2 * i + 1] = *(const f32x4*)(p + 4);
        }
    }
#pragma unroll
    for (int i = 0; i < 4; ++i) {
        const int s = i * 256 + tid;
        if (isf_a) {
            short8 tv;
#pragma unroll
            for (int j = 0; j < 4; ++j) {
                tv[j] = (short)f2b(ar[2 * i][j]);
                tv[4 + j] = (short)f2b(ar[2 * i + 1][j]);
            }
            areg[i] = tv;
        }
        *(short8*)(At + (size_t)s * 8) = areg[i];
        *(short8*)(Bt + (size_t)s * 8) = wreg[i];
    }
    __syncthreads();

#pragma unroll 1
    for (int kt = 0; kt < KITERS; ++kt) {
        // ---- issue next tile's global loads (hide under this tile's MFMA) ----
        if (kt + 1 < KITERS) {
            const int k0 = (kt + 1) * 64;
#pragma unroll
            for (int i = 0; i < 4; ++i) {
                const int s = i * 256 + tid;
                const int row = s >> 3;
                const int gc = (s & 7) ^ (row & 7);
                wreg[i] = *(const short8*)(Wt + (size_t)(n0 + row) * lda + k0 + gc * 8);
                if (!isf_a) {
                    areg[i] = *(const short8*)((const uint16_t*)Av + (size_t)(m0 + row) * lda + k0 + gc * 8);
                } else {
                    const float* p = (const float*)Av + (size_t)(m0 + row) * lda + k0 + gc * 8;
                    ar[2 * i] = *(const f32x4*)p;
                    ar[2 * i + 1] = *(const f32x4*)(p + 4);
                }
            }
        }
        // ---- compute on current LDS tile ----
#pragma unroll
        for (int ks = 0; ks < 2; ++ks) {
            short8 af[4], bf[4];
#pragma unroll
            for (int mt = 0; mt < 4; ++mt) {
                const int row = wr * 64 + mt * 16 + cl;
                const int slot = row * 8 + ((ks * 4 + quad) ^ (row & 7));
                af[mt] = *(const short8*)(At + slot * 8);
            }
#pragma unroll
            for (int nt = 0; nt < 4; ++nt) {
                const int row = wc * 64 + nt * 16 + cl;
                const int slot = row * 8 + ((ks * 4 + quad) ^ (row & 7));
                bf[nt] = *(const short8*)(Bt + slot * 8);
            }
#pragma unroll
            for (int mt = 0; mt < 4; ++mt)
#pragma unroll
                for (int nt = 0; nt < 4; ++nt)
                    acc[mt][nt] = __builtin_amdgcn_mfma_f32_16x16x32_bf16(af[mt], bf[nt], acc[mt][nt], 0, 0, 0);
        }
        // ---- commit prefetched tile to LDS (convert f32 here) ----
        if (kt + 1 < KITERS) {
            __syncthreads();  // all waves done reading current tile
#pragma unroll
            for (int i = 0; i < 4; ++i) {
                const int s = i * 256 + tid;
                if (isf_a) {
                    short8 tv;
#pragma unroll
                    for (int j = 0; j < 4; ++j) {
                        tv[j] = (short)f2b(ar[2 * i][j]);
                        tv[4 + j] = (short)f2b(ar[2 * i + 1][j]);
                    }
                    areg[i] = tv;
                }
                *(short8*)(At + (size_t)s * 8) = areg[i];
                *(short8*)(Bt + (size_t)s * 8) = wreg[i];
            }
            __syncthreads();  // new tile visible to all waves
        }
    }
    // Epilogue. C/D layout (m89-verified): col=lane&15, row=quad*4+reg.
#pragma unroll
    for (int nt = 0; nt < 4; ++nt) {
        const int col = n0 + wc * 64 + nt * 16 + cl;
        const float bv = isf_bias ? ((const float*)biasv)[col] : b2f(((const uint16_t*)biasv)[col]);
#pragma unroll
        for (int mt = 0; mt < 4; ++mt)
#pragma unroll
            for (int r = 0; r < 4; ++r) {
                const int rowg = m0 + wr * 64 + mt * 16 + quad * 4 + r;
                const size_t off = (size_t)rowg * 512 + col;
                const float v = acc[mt][nt][r] + bv;
                if (!isf_c) ((uint16_t*)Cv)[off] = f2b(v);
                else        ((float*)Cv)[off] = v;
            }
    }
}

__global__ __launch_bounds__(256, 2) void k_gemm_proj(
    const void* qi, const void* ki, const void* vi,
    const uint16_t* wtq, const uint16_t* wtk, const uint16_t* wtv,
    const void* bq, const void* bk, const void* bv,
    uint16_t* cq, uint16_t* ck, uint16_t* cv, const int* flag) {
    const int isf = *flag;
    const int z = blockIdx.z;
    const void* A = (z == 0) ? qi : (z == 1) ? ki : vi;
    const uint16_t* W = (z == 0) ? wtq : (z == 1) ? wtk : wtv;
    const void* B = (z == 0) ? bq : (z == 1) ? bk : bv;
    uint16_t* C = (z == 0) ? cq : (z == 1) ? ck : cv;
    gemm_dev<2>(A, 128, W, B, C, isf, isf, 0);   // C always bf16 (internal)
}

__global__ __launch_bounds__(256, 2) void k_gemm_out(
    const uint16_t* __restrict__ A, const uint16_t* __restrict__ Wt,
    const void* __restrict__ bias, void* __restrict__ C, const int* flag) {
    const int isf = *flag;
    gemm_dev<8>(A, 512, Wt, bias, C, 0, isf, isf);  // A always bf16 (internal)
}

// ---------------------------------------------------------------------------
// Attention v4 (unchanged from round 3 -- measured good): block per (bn,head);
// 4 waves x 64 query rows; flash loop over 4 key-tiles of 64; K/V double-
// buffered with prefetch; in-register P via swapped QK^T + pi-permuted V.
// ---------------------------------------------------------------------------
__global__ __launch_bounds__(256, 2) void k_attn(const uint16_t* __restrict__ qws,
                                                 const uint16_t* __restrict__ kws,
                                                 const uint16_t* __restrict__ vws,
                                                 uint16_t* __restrict__ ows) {
    // uint16 element offsets into sm (32 KB total):
    //   Kb[buf]: buf*4096            (64 rows x 8 chunks x 8, chunk-XOR swizzled)
    //   Vt[buf]: 8192 + buf*4096     (64 dims x 64 key-slots, pi-permuted + swizzled)
    __shared__ __align__(16) uint16_t sm[16384];

    const int bx = blockIdx.x;
    const int bn = bx >> 3, h = bx & 7;
    const int tid = threadIdx.x;
    const int lane = tid & 63, w = tid >> 6;
    const int quad = lane >> 4, cl = lane & 15;
    const size_t base = (size_t)bn * 256 * 512 + h * 64;
    const int qbase = w * 64;

    // Q fragments (B-operand of swapped QK; same layout as A-frag):
    // lane holds Q[qbase+mt*16+cl][ks*32+quad*8+j]
    short8 qf[4][2];
#pragma unroll
    for (int mt = 0; mt < 4; ++mt)
#pragma unroll
        for (int ks = 0; ks < 2; ++ks)
            qf[mt][ks] = *(const short8*)(qws + base + (size_t)(qbase + mt * 16 + cl) * 512 + ks * 32 + quad * 8);

    f32x4 O[4][4];
    float lsum[4];
#pragma unroll
    for (int mt = 0; mt < 4; ++mt) {
#pragma unroll
        for (int nt = 0; nt < 4; ++nt) O[mt][nt] = (f32x4){0.f, 0.f, 0.f, 0.f};
        lsum[mt] = 0.f;
    }

    short8 vreg[2];
    // ---- prologue: stage tile 0 into buffer 0 ----
    {
#pragma unroll
        for (int i = 0; i < 2; ++i) {
            const int s = i * 256 + tid;
            const int row = s >> 3;
            const int gc = (s & 7) ^ (row & 7);
            __builtin_amdgcn_global_load_lds(AS1(kws + base + (size_t)row * 512 + gc * 8),
                                             AS3(sm + (i * 256 + w * 64) * 8), 16, 0, 0);
        }
#pragma unroll
        for (int i = 0; i < 2; ++i) {
            const int it = i * 256 + tid;
            const int key = it >> 3, db = (it & 7) * 8;
            vreg[i] = *(const short8*)(vws + base + (size_t)key * 512 + db);
        }
        // V write with pi-permuted key->slot map: slot chunk c=(key>>5)*4+((key>>2)&3),
        // elem j2=((key>>4)&1)*4+(key&3); chunk XOR-swizzled by fd per d-row.
#pragma unroll
        for (int i = 0; i < 2; ++i) {
            const int it = i * 256 + tid;
            const int key = it >> 3, db = (it & 7) * 8;
            const int c = ((key >> 5) & 1) * 4 + ((key >> 2) & 3);
            const int j2 = ((key >> 4) & 1) * 4 + (key & 3);
#pragma unroll
            for (int j = 0; j < 8; ++j) {
                const int d = db + j;
                const int fd = ((d >> 3) ^ d) & 7;
                sm[8192 + d * 64 + ((c ^ fd) & 7) * 8 + j2] = (uint16_t)vreg[i][j];
            }
        }
    }
    __syncthreads();

    int cur = 0;
#pragma unroll 1
    for (int kb = 0; kb < 4; ++kb) {
        const uint16_t* const Kc = sm + cur * 4096;
        const uint16_t* const Vc = sm + 8192 + cur * 4096;
        const int nb = cur ^ 1;

        // ---- issue next tile's loads (fly under this tile's compute) ----
        if (kb < 3) {
#pragma unroll
            for (int i = 0; i < 2; ++i) {
                const int s = i * 256 + tid;
                const int row = s >> 3;
                const int gc = (s & 7) ^ (row & 7);
                __builtin_amdgcn_global_load_lds(AS1(kws + base + (size_t)((kb + 1) * 64 + row) * 512 + gc * 8),
                                                 AS3(sm + nb * 4096 + (i * 256 + w * 64) * 8), 16, 0, 0);
            }
#pragma unroll
            for (int i = 0; i < 2; ++i) {
                const int it = i * 256 + tid;
                const int key = it >> 3, db = (it & 7) * 8;
                vreg[i] = *(const short8*)(vws + base + (size_t)((kb + 1) * 64 + key) * 512 + db);
            }
        }

        // ---- compute on current tile: two key-halves of 32 ----
#pragma unroll
        for (int hf = 0; hf < 2; ++hf) {
            // K fragments for this half: global nt = hf*2 + nt2
            short8 kf[2][2];
#pragma unroll
            for (int nt2 = 0; nt2 < 2; ++nt2)
#pragma unroll
                for (int ks = 0; ks < 2; ++ks) {
                    const int row = (hf * 2 + nt2) * 16 + cl;
                    const int slot = row * 8 + ((ks * 4 + quad) ^ (row & 7));
                    kf[nt2][ks] = *(const short8*)(Kc + slot * 8);
                }
            // V fragments for this half's PV step (chunk hf*4+quad, pi order)
            short8 vf[4];
#pragma unroll
            for (int nt = 0; nt < 4; ++nt) {
                const int d = nt * 16 + cl;
                const int fd = ((d >> 3) ^ d) & 7;
                vf[nt] = *(const short8*)(Vc + d * 64 + (((hf * 4 + quad) ^ fd) & 7) * 8);
            }
#pragma unroll
            for (int mt = 0; mt < 4; ++mt) {
                // swapped QK: S2[key][q], lane holds q=cl, key=(hf*2+nt2)*16+quad*4+r
                f32x4 S0 = (f32x4){0.f, 0.f, 0.f, 0.f};
                f32x4 S1 = (f32x4){0.f, 0.f, 0.f, 0.f};
#pragma unroll
                for (int ks = 0; ks < 2; ++ks) {
                    S0 = __builtin_amdgcn_mfma_f32_16x16x32_bf16(kf[0][ks], qf[mt][ks], S0, 0, 0, 0);
                    S1 = __builtin_amdgcn_mfma_f32_16x16x32_bf16(kf[1][ks], qf[mt][ks], S1, 0, 0, 0);
                }
                // exp + pack into the PV A-fragment (pi-matched: j>>2 -> nt2, j&3 -> r)
                short8 pf;
                float ls = 0.f;
#pragma unroll
                for (int r = 0; r < 4; ++r) {
                    const float pv = __expf(S0[r] * 0.125f);
                    ls += pv;
                    pf[r] = (short)f2b(pv);
                }
#pragma unroll
                for (int r = 0; r < 4; ++r) {
                    const float pv = __expf(S1[r] * 0.125f);
                    ls += pv;
                    pf[4 + r] = (short)f2b(pv);
                }
                lsum[mt] += ls;
#pragma unroll
                for (int nt = 0; nt < 4; ++nt)
                    O[mt][nt] = __builtin_amdgcn_mfma_f32_16x16x32_bf16(pf, vf[nt], O[mt][nt], 0, 0, 0);
            }
        }

        // ---- late half of V staging: pi-permuted ds_writes into next buffer ----
        if (kb < 3) {
#pragma unroll
            for (int i = 0; i < 2; ++i) {
                const int it = i * 256 + tid;
                const int key = it >> 3, db = (it & 7) * 8;
                const int c = ((key >> 5) & 1) * 4 + ((key >> 2) & 3);
                const int j2 = ((key >> 4) & 1) * 4 + (key & 3);
#pragma unroll
                for (int j = 0; j < 8; ++j) {
                    const int d = db + j;
                    const int fd = ((d >> 3) ^ d) & 7;
                    sm[8192 + nb * 4096 + d * 64 + ((c ^ fd) & 7) * 8 + j2] = (uint16_t)vreg[i][j];
                }
            }
        }
        __syncthreads();  // next tile fully staged; everyone done reading cur
        cur = nb;
    }

    // Row-sum: lane holds the partial for q=mt*16+cl over its quad's keys;
    // combine the 4 quads (lanes cl, cl+16, cl+32, cl+48).
    float linv[4];
#pragma unroll
    for (int mt = 0; mt < 4; ++mt) {
        float v = lsum[mt];
        v += __shfl_xor(v, 16, 64);
        v += __shfl_xor(v, 32, 64);
        linv[mt] = 1.0f / v;
    }

    // Epilogue: O layout is q=mt*16+quad*4+r, d=nt*16+cl. Normalizer for row
    // quad*4+r lives at lane cl=quad*4+r (any quad). Bounce normalized bf16 O
    // through the dead K/V LDS (chunk-XOR swizzled), then stores where one
    // instruction's 64 lanes cover 8 complete 128B row-slices.
    uint16_t* const Ob = sm + w * 4096;
#pragma unroll
    for (int mt = 0; mt < 4; ++mt) {
        float ln4[4];
#pragma unroll
        for (int r = 0; r < 4; ++r) ln4[r] = __shfl(linv[mt], quad * 4 + r, 64);
#pragma unroll
        for (int nt = 0; nt < 4; ++nt)
#pragma unroll
            for (int r = 0; r < 4; ++r) {
                const int row = mt * 16 + quad * 4 + r;
                const int col = nt * 16 + cl;
                Ob[row * 64 + ((((col >> 3) ^ (row & 7)) & 7) * 8 + (col & 7))] =
                    f2b(O[mt][nt][r] * ln4[r]);
            }
    }
    // lane -> (row = g*8 + lane>>3, chunk = lane&7): full 64B lines per inst.
#pragma unroll
    for (int g = 0; g < 8; ++g) {
        const int row = g * 8 + (lane >> 3);
        const int c = lane & 7;
        const short8 ov = *(const short8*)(Ob + row * 64 + ((c ^ (row & 7)) & 7) * 8);
        *(short8*)(ows + base + (size_t)(qbase + row) * 512 + c * 8) = ov;
    }
}

// ---------------------------------------------------------------------------
extern "C" void kernel_launch(void* const* d_in, const int* in_sizes, int n_in,
                              void* d_out, int out_size, void* d_ws, size_t ws_size,
                              hipStream_t stream) {
    uint16_t* ws = (uint16_t*)d_ws;

    int* flag = (int*)d_ws;                   // 4 bytes
    uint16_t* wt_q = ws + 256;                // 512x128 bf16
    uint16_t* wt_k = wt_q + 128 * 512;
    uint16_t* wt_v = wt_k + 128 * 512;
    uint16_t* wt_o = wt_v + 128 * 512;        // 512x512 bf16
    uint16_t* q_ws = wt_o + 512 * 512;        // 65536x512 bf16; also attn out
    const size_t QKV = (size_t)65536 * 512;
    uint16_t* k_ws = q_ws + QKV;
    uint16_t* v_ws = k_ws + QKV;
    // total ws use ~193 MiB

    k_detect<<<1, 64, 0, stream>>>((const uint16_t*)d_in[0], flag);
    k_transpose<<<dim3(1024, 4), 256, 0, stream>>>(d_in[3], d_in[5], d_in[7], d_in[9],
                                                   wt_q, wt_k, wt_v, wt_o, flag);
    // n-tile on x (fast axis) for A-tile L2/L3 reuse across the 4 n-blocks.
    k_gemm_proj<<<dim3(4, 512, 3), 256, 0, stream>>>(d_in[0], d_in[1], d_in[2],
                                                     wt_q, wt_k, wt_v,
                                                     d_in[4], d_in[6], d_in[8],
                                                     q_ws, k_ws, v_ws, flag);
    k_attn<<<dim3(2048), 256, 0, stream>>>(q_ws, k_ws, v_ws, q_ws);
    k_gemm_out<<<dim3(4, 512), 256, 0, stream>>>(q_ws, wt_o, d_in[10], d_out, flag);
}

// Round 5
// 476.497 us; speedup vs baseline: 1.2498x; 1.2498x over previous
//
#include <hip/hip_runtime.h>
#include <stdint.h>
#include <stddef.h>

// B=4,N=64 -> BN=256 batches; L=256; IN=128; H=512; heads=8; hd=64.
// Inputs may be bf16 OR float32 (harness-dependent) -> runtime-detected flag.
// All internal compute: bf16 MFMA + fp32 accumulate.

typedef __attribute__((ext_vector_type(8))) short short8;
typedef __attribute__((ext_vector_type(4))) float f32x4;

#define AS1(p) ((const __attribute__((address_space(1))) void*)(p))
#define AS3(p) ((__attribute__((address_space(3))) void*)(p))

__device__ __forceinline__ float b2f(uint16_t u) {
    union { uint32_t i; float f; } x; x.i = ((uint32_t)u) << 16; return x.f;
}
__device__ __forceinline__ uint16_t f2b(float f) {
    union { float f; uint32_t i; } x; x.f = f;
    uint32_t r = x.i + 0x7fffu + ((x.i >> 16) & 1u);  // RNE
    return (uint16_t)(r >> 16);
}

// ---------------------------------------------------------------------------
// Dtype sniffer: bf16 N(0,1) data -> exponent field in ~[110,135] (outliers
// ~0%). float32 data read as uint16: even elements are f32 low-mantissa
// halves -> ~uniform exponent bits -> ~42% outliers. flag=1 means float32.
// ---------------------------------------------------------------------------
__global__ void k_detect(const uint16_t* __restrict__ q, int* __restrict__ flag) {
    const int t = threadIdx.x;
    int cnt = 0;
    for (int i = 0; i < 32; ++i) {
        const int e = (q[t * 32 + i] >> 7) & 0xff;
        cnt += (e < 110) | (e > 135);
    }
#pragma unroll
    for (int m = 1; m < 64; m <<= 1) cnt += __shfl_xor(cnt, m, 64);
    if (t == 0) *flag = (cnt > 256) ? 1 : 0;
}

__device__ __forceinline__ uint16_t rd_any(const void* p, size_t idx, int isf) {
    return isf ? f2b(((const float*)p)[idx]) : ((const uint16_t*)p)[idx];
}

// ---------------------------------------------------------------------------
// Transpose weights W (K x 512) -> Wt (512 x K) bf16, so GEMM B-fragments
// read 16B contiguous along k. Tiny, L2-resident.
// ---------------------------------------------------------------------------
__global__ void k_transpose(const void* __restrict__ Wq, const void* __restrict__ Wk,
                            const void* __restrict__ Wv, const void* __restrict__ Wo,
                            uint16_t* __restrict__ wtq, uint16_t* __restrict__ wtk,
                            uint16_t* __restrict__ wtv, uint16_t* __restrict__ wto,
                            const int* __restrict__ flag) {
    const int isf = *flag;
    const int z = blockIdx.y;
    const int t = blockIdx.x * 256 + threadIdx.x;
    if (z < 3) {
        if (t >= 128 * 512) return;
        const void* W = (z == 0) ? Wq : (z == 1) ? Wk : Wv;
        uint16_t* o = (z == 0) ? wtq : (z == 1) ? wtk : wtv;
        const int k = t & 127, n = t >> 7;
        o[t] = rd_any(W, (size_t)k * 512 + n, isf);   // o[n*128+k] = W[k][n]
    } else {
        const int k = t & 511, n = t >> 9;
        wto[t] = rd_any(Wo, (size_t)k * 512 + n, isf);
    }
}

// ---------------------------------------------------------------------------
// GEMM v5: C(M x 512) = A(M x K) @ Wt(512 x K)^T + bias. 128x128 tile,
// BK=128 (v5: whole-K stages, was 64), 4 waves 2x2, 16x16x32 bf16 MFMA.
//
// Round-4 lesson (counters): ANY scheme keeping a staged tile in VGPRs across
// the MFMA cluster spills (VGPR cap 128 w/ MFMA arch-split) -> 540 MB scratch
// writes to HBM. So staging is global_load_lds (bf16) / inline convert+ds_write
// (f32 A), ZERO persistent staging registers (round-3 measured-good form).
//
// BK=128 halves the exposed stage->vmcnt(0)->compute round trips: proj does
// ONE stage burst per block (KITERS=1, no mid-loop barriers at all), out does
// 4 instead of 8. LDS 64 KB; launch_bounds(256,2) already capped us at
// 2 blocks/CU, so no occupancy loss.
//
// LDS layout: row-major [128][16 chunks of 16B], chunk slot sc holds global
// chunk (sc&8)|((sc&7)^(row&7)) -> ds_read_b128 fragment reads are 2-way
// (free); staging dest is LINEAR (gload_lds constraint), source pre-permuted.
//
// Epilogue (bf16 C): bounce through LDS (wave-private 8KB quarter, chunk-XOR
// swizzle) then full-line short8 stores (port of the measured-good attn
// epilogue; removes the 64x 2B scalar scatter). f32 C keeps scalar stores
// (16 lanes x 4B already cover full 64B lines).
//
// Grid: n-tile fastest -> 4 consecutive blocks share one A-tile (L2 reuse).
// ---------------------------------------------------------------------------
template<int KITERS>
__device__ __forceinline__ void gemm_dev(const void* __restrict__ Av, const int lda,
                                         const uint16_t* __restrict__ Wt,
                                         const void* __restrict__ biasv,
                                         void* __restrict__ Cv,
                                         const int isf_a, const int isf_bias, const int isf_c) {
    __shared__ __align__(16) uint16_t smA[128 * 128];
    __shared__ __align__(16) uint16_t smB[128 * 128];
    const int n0 = blockIdx.x * 128, m0 = blockIdx.y * 128;  // n = fast axis
    const int tid = threadIdx.x;
    const int lane = tid & 63, w = tid >> 6;
    const int wr = w >> 1, wc = w & 1;
    const int quad = lane >> 4, cl = lane & 15;

    f32x4 acc[4][4];
#pragma unroll
    for (int i = 0; i < 4; ++i)
#pragma unroll
        for (int j = 0; j < 4; ++j) acc[i][j] = (f32x4){0.f, 0.f, 0.f, 0.f};

#pragma unroll 1
    for (int kt = 0; kt < KITERS; ++kt) {
        const int k0 = kt * 128;
        __syncthreads();  // protect LDS from previous iteration's readers
#pragma unroll
        for (int i = 0; i < 8; ++i) {
            const int s = i * 256 + tid;          // 2048 chunk-slots of 16B
            const int row = s >> 4;
            const int sc = s & 15;
            const int gc = (sc & 8) | ((sc & 7) ^ (row & 7));
            __builtin_amdgcn_global_load_lds(AS1(Wt + (size_t)(n0 + row) * lda + k0 + gc * 8),
                                             AS3(smB + (size_t)(i * 256 + w * 64) * 8), 16, 0, 0);
            if (!isf_a) {
                __builtin_amdgcn_global_load_lds(AS1((const uint16_t*)Av + (size_t)(m0 + row) * lda + k0 + gc * 8),
                                                 AS3(smA + (size_t)(i * 256 + w * 64) * 8), 16, 0, 0);
            } else {
                const float* p = (const float*)Av + (size_t)(m0 + row) * lda + k0 + gc * 8;
                const f32x4 u0 = *(const f32x4*)p;
                const f32x4 u1 = *(const f32x4*)(p + 4);
                short8 tv;
#pragma unroll
                for (int j = 0; j < 4; ++j) {
                    tv[j] = (short)f2b(u0[j]);
                    tv[4 + j] = (short)f2b(u1[j]);
                }
                *(short8*)(smA + (size_t)s * 8) = tv;
            }
        }
        __syncthreads();
#pragma unroll
        for (int ks = 0; ks < 4; ++ks) {
            short8 af[4], bf[4];
#pragma unroll
            for (int mt = 0; mt < 4; ++mt) {
                const int row = wr * 64 + mt * 16 + cl;
                const int q = ks * 4 + quad;
                const int sc = (q & 8) | ((q & 7) ^ (row & 7));
                af[mt] = *(const short8*)(smA + (row * 16 + sc) * 8);
            }
#pragma unroll
            for (int nt = 0; nt < 4; ++nt) {
                const int row = wc * 64 + nt * 16 + cl;
                const int q = ks * 4 + quad;
                const int sc = (q & 8) | ((q & 7) ^ (row & 7));
                bf[nt] = *(const short8*)(smB + (row * 16 + sc) * 8);
            }
#pragma unroll
            for (int mt = 0; mt < 4; ++mt)
#pragma unroll
                for (int nt = 0; nt < 4; ++nt)
                    acc[mt][nt] = __builtin_amdgcn_mfma_f32_16x16x32_bf16(af[mt], bf[nt], acc[mt][nt], 0, 0, 0);
        }
    }
    // Epilogue. C/D layout (m89-verified): col=lane&15, row=quad*4+reg.
    if (!isf_c) {
        // bf16 C: bounce through wave-private LDS quarter, full-line stores.
        __syncthreads();  // all waves done reading smA/smB
        uint16_t* const Ob = smA + w * 4096;  // 64x64 bf16, chunk-XOR swizzled
#pragma unroll
        for (int nt = 0; nt < 4; ++nt) {
            const int col = nt * 16 + cl;  // wave-local col
            const float bv = isf_bias ? ((const float*)biasv)[n0 + wc * 64 + col]
                                      : b2f(((const uint16_t*)biasv)[n0 + wc * 64 + col]);
#pragma unroll
            for (int mt = 0; mt < 4; ++mt)
#pragma unroll
                for (int r = 0; r < 4; ++r) {
                    const int row = mt * 16 + quad * 4 + r;  // wave-local row
                    Ob[row * 64 + (((col >> 3) ^ (row & 7)) & 7) * 8 + (col & 7)] =
                        f2b(acc[mt][nt][r] + bv);
                }
        }
#pragma unroll
        for (int g = 0; g < 8; ++g) {
            const int row = g * 8 + (lane >> 3);
            const int c = lane & 7;
            const short8 ov = *(const short8*)(Ob + row * 64 + ((c ^ (row & 7)) & 7) * 8);
            *(short8*)((uint16_t*)Cv + (size_t)(m0 + wr * 64 + row) * 512 + n0 + wc * 64 + c * 8) = ov;
        }
    } else {
#pragma unroll
        for (int nt = 0; nt < 4; ++nt) {
            const int col = n0 + wc * 64 + nt * 16 + cl;
            const float bv = isf_bias ? ((const float*)biasv)[col] : b2f(((const uint16_t*)biasv)[col]);
#pragma unroll
            for (int mt = 0; mt < 4; ++mt)
#pragma unroll
                for (int r = 0; r < 4; ++r) {
                    const int rowg = m0 + wr * 64 + mt * 16 + quad * 4 + r;
                    ((float*)Cv)[(size_t)rowg * 512 + col] = acc[mt][nt][r] + bv;
                }
        }
    }
}

__global__ __launch_bounds__(256, 2) void k_gemm_proj(
    const void* qi, const void* ki, const void* vi,
    const uint16_t* wtq, const uint16_t* wtk, const uint16_t* wtv,
    const void* bq, const void* bk, const void* bv,
    uint16_t* cq, uint16_t* ck, uint16_t* cv, const int* flag) {
    const int isf = *flag;
    const int z = blockIdx.z;
    const void* A = (z == 0) ? qi : (z == 1) ? ki : vi;
    const uint16_t* W = (z == 0) ? wtq : (z == 1) ? wtk : wtv;
    const void* B = (z == 0) ? bq : (z == 1) ? bk : bv;
    uint16_t* C = (z == 0) ? cq : (z == 1) ? ck : cv;
    gemm_dev<1>(A, 128, W, B, C, isf, isf, 0);   // C always bf16 (internal)
}

__global__ __launch_bounds__(256, 2) void k_gemm_out(
    const uint16_t* __restrict__ A, const uint16_t* __restrict__ Wt,
    const void* __restrict__ bias, void* __restrict__ C, const int* flag) {
    const int isf = *flag;
    gemm_dev<4>(A, 512, Wt, bias, C, 0, isf, isf);  // A always bf16 (internal)
}

// ---------------------------------------------------------------------------
// Attention v4 (unchanged -- measured good): block per (bn,head);
// 4 waves x 64 query rows; flash loop over 4 key-tiles of 64; K/V double-
// buffered with prefetch; in-register P via swapped QK^T + pi-permuted V.
// ---------------------------------------------------------------------------
__global__ __launch_bounds__(256, 2) void k_attn(const uint16_t* __restrict__ qws,
                                                 const uint16_t* __restrict__ kws,
                                                 const uint16_t* __restrict__ vws,
                                                 uint16_t* __restrict__ ows) {
    // uint16 element offsets into sm (32 KB total):
    //   Kb[buf]: buf*4096            (64 rows x 8 chunks x 8, chunk-XOR swizzled)
    //   Vt[buf]: 8192 + buf*4096     (64 dims x 64 key-slots, pi-permuted + swizzled)
    __shared__ __align__(16) uint16_t sm[16384];

    const int bx = blockIdx.x;
    const int bn = bx >> 3, h = bx & 7;
    const int tid = threadIdx.x;
    const int lane = tid & 63, w = tid >> 6;
    const int quad = lane >> 4, cl = lane & 15;
    const size_t base = (size_t)bn * 256 * 512 + h * 64;
    const int qbase = w * 64;

    // Q fragments (B-operand of swapped QK; same layout as A-frag):
    // lane holds Q[qbase+mt*16+cl][ks*32+quad*8+j]
    short8 qf[4][2];
#pragma unroll
    for (int mt = 0; mt < 4; ++mt)
#pragma unroll
        for (int ks = 0; ks < 2; ++ks)
            qf[mt][ks] = *(const short8*)(qws + base + (size_t)(qbase + mt * 16 + cl) * 512 + ks * 32 + quad * 8);

    f32x4 O[4][4];
    float lsum[4];
#pragma unroll
    for (int mt = 0; mt < 4; ++mt) {
#pragma unroll
        for (int nt = 0; nt < 4; ++nt) O[mt][nt] = (f32x4){0.f, 0.f, 0.f, 0.f};
        lsum[mt] = 0.f;
    }

    short8 vreg[2];
    // ---- prologue: stage tile 0 into buffer 0 ----
    {
#pragma unroll
        for (int i = 0; i < 2; ++i) {
            const int s = i * 256 + tid;
            const int row = s >> 3;
            const int gc = (s & 7) ^ (row & 7);
            __builtin_amdgcn_global_load_lds(AS1(kws + base + (size_t)row * 512 + gc * 8),
                                             AS3(sm + (i * 256 + w * 64) * 8), 16, 0, 0);
        }
#pragma unroll
        for (int i = 0; i < 2; ++i) {
            const int it = i * 256 + tid;
            const int key = it >> 3, db = (it & 7) * 8;
            vreg[i] = *(const short8*)(vws + base + (size_t)key * 512 + db);
        }
        // V write with pi-permuted key->slot map: slot chunk c=(key>>5)*4+((key>>2)&3),
        // elem j2=((key>>4)&1)*4+(key&3); chunk XOR-swizzled by fd per d-row.
#pragma unroll
        for (int i = 0; i < 2; ++i) {
            const int it = i * 256 + tid;
            const int key = it >> 3, db = (it & 7) * 8;
            const int c = ((key >> 5) & 1) * 4 + ((key >> 2) & 3);
            const int j2 = ((key >> 4) & 1) * 4 + (key & 3);
#pragma unroll
            for (int j = 0; j < 8; ++j) {
                const int d = db + j;
                const int fd = ((d >> 3) ^ d) & 7;
                sm[8192 + d * 64 + ((c ^ fd) & 7) * 8 + j2] = (uint16_t)vreg[i][j];
            }
        }
    }
    __syncthreads();

    int cur = 0;
#pragma unroll 1
    for (int kb = 0; kb < 4; ++kb) {
        const uint16_t* const Kc = sm + cur * 4096;
        const uint16_t* const Vc = sm + 8192 + cur * 4096;
        const int nb = cur ^ 1;

        // ---- issue next tile's loads (fly under this tile's compute) ----
        if (kb < 3) {
#pragma unroll
            for (int i = 0; i < 2; ++i) {
                const int s = i * 256 + tid;
                const int row = s >> 3;
                const int gc = (s & 7) ^ (row & 7);
                __builtin_amdgcn_global_load_lds(AS1(kws + base + (size_t)((kb + 1) * 64 + row) * 512 + gc * 8),
                                                 AS3(sm + nb * 4096 + (i * 256 + w * 64) * 8), 16, 0, 0);
            }
#pragma unroll
            for (int i = 0; i < 2; ++i) {
                const int it = i * 256 + tid;
                const int key = it >> 3, db = (it & 7) * 8;
                vreg[i] = *(const short8*)(vws + base + (size_t)((kb + 1) * 64 + key) * 512 + db);
            }
        }

        // ---- compute on current tile: two key-halves of 32 ----
#pragma unroll
        for (int hf = 0; hf < 2; ++hf) {
            // K fragments for this half: global nt = hf*2 + nt2
            short8 kf[2][2];
#pragma unroll
            for (int nt2 = 0; nt2 < 2; ++nt2)
#pragma unroll
                for (int ks = 0; ks < 2; ++ks) {
                    const int row = (hf * 2 + nt2) * 16 + cl;
                    const int slot = row * 8 + ((ks * 4 + quad) ^ (row & 7));
                    kf[nt2][ks] = *(const short8*)(Kc + slot * 8);
                }
            // V fragments for this half's PV step (chunk hf*4+quad, pi order)
            short8 vf[4];
#pragma unroll
            for (int nt = 0; nt < 4; ++nt) {
                const int d = nt * 16 + cl;
                const int fd = ((d >> 3) ^ d) & 7;
                vf[nt] = *(const short8*)(Vc + d * 64 + (((hf * 4 + quad) ^ fd) & 7) * 8);
            }
#pragma unroll
            for (int mt = 0; mt < 4; ++mt) {
                // swapped QK: S2[key][q], lane holds q=cl, key=(hf*2+nt2)*16+quad*4+r
                f32x4 S0 = (f32x4){0.f, 0.f, 0.f, 0.f};
                f32x4 S1 = (f32x4){0.f, 0.f, 0.f, 0.f};
#pragma unroll
                for (int ks = 0; ks < 2; ++ks) {
                    S0 = __builtin_amdgcn_mfma_f32_16x16x32_bf16(kf[0][ks], qf[mt][ks], S0, 0, 0, 0);
                    S1 = __builtin_amdgcn_mfma_f32_16x16x32_bf16(kf[1][ks], qf[mt][ks], S1, 0, 0, 0);
                }
                // exp + pack into the PV A-fragment (pi-matched: j>>2 -> nt2, j&3 -> r)
                short8 pf;
                float ls = 0.f;
#pragma unroll
                for (int r = 0; r < 4; ++r) {
                    const float pv = __expf(S0[r] * 0.125f);
                    ls += pv;
                    pf[r] = (short)f2b(pv);
                }
#pragma unroll
                for (int r = 0; r < 4; ++r) {
                    const float pv = __expf(S1[r] * 0.125f);
                    ls += pv;
                    pf[4 + r] = (short)f2b(pv);
                }
                lsum[mt] += ls;
#pragma unroll
                for (int nt = 0; nt < 4; ++nt)
                    O[mt][nt] = __builtin_amdgcn_mfma_f32_16x16x32_bf16(pf, vf[nt], O[mt][nt], 0, 0, 0);
            }
        }

        // ---- late half of V staging: pi-permuted ds_writes into next buffer ----
        if (kb < 3) {
#pragma unroll
            for (int i = 0; i < 2; ++i) {
                const int it = i * 256 + tid;
                const int key = it >> 3, db = (it & 7) * 8;
                const int c = ((key >> 5) & 1) * 4 + ((key >> 2) & 3);
                const int j2 = ((key >> 4) & 1) * 4 + (key & 3);
#pragma unroll
                for (int j = 0; j < 8; ++j) {
                    const int d = db + j;
                    const int fd = ((d >> 3) ^ d) & 7;
                    sm[8192 + nb * 4096 + d * 64 + ((c ^ fd) & 7) * 8 + j2] = (uint16_t)vreg[i][j];
                }
            }
        }
        __syncthreads();  // next tile fully staged; everyone done reading cur
        cur = nb;
    }

    // Row-sum: lane holds the partial for q=mt*16+cl over its quad's keys;
    // combine the 4 quads (lanes cl, cl+16, cl+32, cl+48).
    float linv[4];
#pragma unroll
    for (int mt = 0; mt < 4; ++mt) {
        float v = lsum[mt];
        v += __shfl_xor(v, 16, 64);
        v += __shfl_xor(v, 32, 64);
        linv[mt] = 1.0f / v;
    }

    // Epilogue: O layout is q=mt*16+quad*4+r, d=nt*16+cl. Normalizer for row
    // quad*4+r lives at lane cl=quad*4+r (any quad). Bounce normalized bf16 O
    // through the dead K/V LDS (chunk-XOR swizzled), then stores where one
    // instruction's 64 lanes cover 8 complete 128B row-slices.
    uint16_t* const Ob = sm + w * 4096;
#pragma unroll
    for (int mt = 0; mt < 4; ++mt) {
        float ln4[4];
#pragma unroll
        for (int r = 0; r < 4; ++r) ln4[r] = __shfl(linv[mt], quad * 4 + r, 64);
#pragma unroll
        for (int nt = 0; nt < 4; ++nt)
#pragma unroll
            for (int r = 0; r < 4; ++r) {
                const int row = mt * 16 + quad * 4 + r;
                const int col = nt * 16 + cl;
                Ob[row * 64 + ((((col >> 3) ^ (row & 7)) & 7) * 8 + (col & 7))] =
                    f2b(O[mt][nt][r] * ln4[r]);
            }
    }
    // lane -> (row = g*8 + lane>>3, chunk = lane&7): full 64B lines per inst.
#pragma unroll
    for (int g = 0; g < 8; ++g) {
        const int row = g * 8 + (lane >> 3);
        const int c = lane & 7;
        const short8 ov = *(const short8*)(Ob + row * 64 + ((c ^ (row & 7)) & 7) * 8);
        *(short8*)(ows + base + (size_t)(qbase + row) * 512 + c * 8) = ov;
    }
}

// ---------------------------------------------------------------------------
extern "C" void kernel_launch(void* const* d_in, const int* in_sizes, int n_in,
                              void* d_out, int out_size, void* d_ws, size_t ws_size,
                              hipStream_t stream) {
    uint16_t* ws = (uint16_t*)d_ws;

    int* flag = (int*)d_ws;                   // 4 bytes
    uint16_t* wt_q = ws + 256;                // 512x128 bf16
    uint16_t* wt_k = wt_q + 128 * 512;
    uint16_t* wt_v = wt_k + 128 * 512;
    uint16_t* wt_o = wt_v + 128 * 512;        // 512x512 bf16
    uint16_t* q_ws = wt_o + 512 * 512;        // 65536x512 bf16; also attn out
    const size_t QKV = (size_t)65536 * 512;
    uint16_t* k_ws = q_ws + QKV;
    uint16_t* v_ws = k_ws + QKV;
    // total ws use ~193 MiB

    k_detect<<<1, 64, 0, stream>>>((const uint16_t*)d_in[0], flag);
    k_transpose<<<dim3(1024, 4), 256, 0, stream>>>(d_in[3], d_in[5], d_in[7], d_in[9],
                                                   wt_q, wt_k, wt_v, wt_o, flag);
    // n-tile on x (fast axis) for A-tile L2/L3 reuse across the 4 n-blocks.
    k_gemm_proj<<<dim3(4, 512, 3), 256, 0, stream>>>(d_in[0], d_in[1], d_in[2],
                                                     wt_q, wt_k, wt_v,
                                                     d_in[4], d_in[6], d_in[8],
                                                     q_ws, k_ws, v_ws, flag);
    k_attn<<<dim3(2048), 256, 0, stream>>>(q_ws, k_ws, v_ws, q_ws);
    k_gemm_out<<<dim3(4, 512), 256, 0, stream>>>(q_ws, wt_o, d_in[10], d_out, flag);
}

// Round 6
// 428.559 us; speedup vs baseline: 1.3896x; 1.1119x over previous
//
#include <hip/hip_runtime.h>
#include <stdint.h>
#include <stddef.h>

// B=4,N=64 -> BN=256 batches; L=256; IN=128; H=512; heads=8; hd=64.
// Inputs may be bf16 OR float32 (harness-dependent) -> runtime-detected flag.
// All internal compute: bf16 MFMA + fp32 accumulate.

typedef __attribute__((ext_vector_type(8))) short short8;
typedef __attribute__((ext_vector_type(4))) float f32x4;

#define AS1(p) ((const __attribute__((address_space(1))) void*)(p))
#define AS3(p) ((__attribute__((address_space(3))) void*)(p))

__device__ __forceinline__ float b2f(uint16_t u) {
    union { uint32_t i; float f; } x; x.i = ((uint32_t)u) << 16; return x.f;
}
__device__ __forceinline__ uint16_t f2b(float f) {
    union { float f; uint32_t i; } x; x.f = f;
    uint32_t r = x.i + 0x7fffu + ((x.i >> 16) & 1u);  // RNE
    return (uint16_t)(r >> 16);
}

// ---------------------------------------------------------------------------
// Dtype sniffer: bf16 N(0,1) data -> exponent field in ~[110,135] (outliers
// ~0%). float32 data read as uint16: even elements are f32 low-mantissa
// halves -> ~uniform exponent bits -> ~42% outliers. flag=1 means float32.
// ---------------------------------------------------------------------------
__global__ void k_detect(const uint16_t* __restrict__ q, int* __restrict__ flag) {
    const int t = threadIdx.x;
    int cnt = 0;
    for (int i = 0; i < 32; ++i) {
        const int e = (q[t * 32 + i] >> 7) & 0xff;
        cnt += (e < 110) | (e > 135);
    }
#pragma unroll
    for (int m = 1; m < 64; m <<= 1) cnt += __shfl_xor(cnt, m, 64);
    if (t == 0) *flag = (cnt > 256) ? 1 : 0;
}

__device__ __forceinline__ uint16_t rd_any(const void* p, size_t idx, int isf) {
    return isf ? f2b(((const float*)p)[idx]) : ((const uint16_t*)p)[idx];
}

// ---------------------------------------------------------------------------
// Transpose weights W (K x 512) -> Wt (512 x K) bf16, so GEMM B-fragments
// read 16B contiguous along k. Tiny, L2-resident.
// ---------------------------------------------------------------------------
__global__ void k_transpose(const void* __restrict__ Wq, const void* __restrict__ Wk,
                            const void* __restrict__ Wv, const void* __restrict__ Wo,
                            uint16_t* __restrict__ wtq, uint16_t* __restrict__ wtk,
                            uint16_t* __restrict__ wtv, uint16_t* __restrict__ wto,
                            const int* __restrict__ flag) {
    const int isf = *flag;
    const int z = blockIdx.y;
    const int t = blockIdx.x * 256 + threadIdx.x;
    if (z < 3) {
        if (t >= 128 * 512) return;
        const void* W = (z == 0) ? Wq : (z == 1) ? Wk : Wv;
        uint16_t* o = (z == 0) ? wtq : (z == 1) ? wtk : wtv;
        const int k = t & 127, n = t >> 7;
        o[t] = rd_any(W, (size_t)k * 512 + n, isf);   // o[n*128+k] = W[k][n]
    } else {
        const int k = t & 511, n = t >> 9;
        wto[t] = rd_any(Wo, (size_t)k * 512 + n, isf);
    }
}

// ---------------------------------------------------------------------------
// GEMM v6 = R3 measured-good core (128 us proj) + XCD swizzle + full-line C.
//
// Core (R3): 128x128 tile, BK=64, 4 waves 2x2, 16x16x32 bf16 MFMA, serial
// stage->vmcnt(0)->compute per K-step, single 32KB LDS pair, chunk-XOR
// swizzle, ZERO persistent staging registers.
// Five-round record: reg-prefetch (R4) spills past the 128-VGPR MFMA split
// (540 MB scratch->HBM); BK=128/64KB (R5) halves residency and exposes one
// giant un-hidden stage (170 us). The simple serial form + high residency
// wins. Do not re-add register residency across the MFMA cluster.
//
// New in v6:
//  * Callers pass m0/n0 computed via a bijective XCD-chunk swizzle with the
//    n-tile as the fastest axis: the 4 blocks sharing an A-tile get
//    consecutive nid on the SAME XCD -> A hits that XCD's L2 instead of 4x
//    L3/HBM fetches (R3 FETCH 188 MB vs ~108 ideal; also cuts stage latency).
//  * bf16-C epilogue bounces through wave-private LDS quarters (At/Bt are
//    dead by then) -> full 64B-line short8 stores, removing R3's 1.28x write
//    amplification. f32-C keeps scalar stores (16x4B lanes = full lines).
// ---------------------------------------------------------------------------
template<int KITERS>
__device__ __forceinline__ void gemm_dev(const void* __restrict__ Av, const int lda,
                                         const uint16_t* __restrict__ Wt,
                                         const void* __restrict__ biasv,
                                         void* __restrict__ Cv,
                                         const int m0, const int n0,
                                         const int isf_a, const int isf_bias, const int isf_c) {
    __shared__ __align__(16) uint16_t At[128 * 64];
    __shared__ __align__(16) uint16_t Bt[128 * 64];
    const int tid = threadIdx.x;
    const int lane = tid & 63, w = tid >> 6;
    const int wr = w >> 1, wc = w & 1;
    const int quad = lane >> 4, cl = lane & 15;

    f32x4 acc[4][4];
#pragma unroll
    for (int i = 0; i < 4; ++i)
#pragma unroll
        for (int j = 0; j < 4; ++j) acc[i][j] = (f32x4){0.f, 0.f, 0.f, 0.f};

#pragma unroll 1
    for (int kt = 0; kt < KITERS; ++kt) {
        const int k0 = kt * 64;
        __syncthreads();  // protect LDS from previous iteration's readers
        if (!isf_a) {
#pragma unroll
            for (int i = 0; i < 4; ++i) {
                const int s = i * 256 + tid;
                const int row = s >> 3;
                const int gc = (s & 7) ^ (row & 7);
                __builtin_amdgcn_global_load_lds(AS1((const uint16_t*)Av + (size_t)(m0 + row) * lda + k0 + gc * 8),
                                                 AS3(At + (size_t)(i * 256 + w * 64) * 8), 16, 0, 0);
                __builtin_amdgcn_global_load_lds(AS1(Wt + (size_t)(n0 + row) * lda + k0 + gc * 8),
                                                 AS3(Bt + (size_t)(i * 256 + w * 64) * 8), 16, 0, 0);
            }
        } else {
#pragma unroll
            for (int i = 0; i < 4; ++i) {
                const int s = i * 256 + tid;
                const int row = s >> 3;
                const int gc = (s & 7) ^ (row & 7);
                __builtin_amdgcn_global_load_lds(AS1(Wt + (size_t)(n0 + row) * lda + k0 + gc * 8),
                                                 AS3(Bt + (size_t)(i * 256 + w * 64) * 8), 16, 0, 0);
                const float* p = (const float*)Av + (size_t)(m0 + row) * lda + k0 + gc * 8;
                const f32x4 u0 = *(const f32x4*)p;
                const f32x4 u1 = *(const f32x4*)(p + 4);
                short8 tv;
#pragma unroll
                for (int j = 0; j < 4; ++j) {
                    tv[j] = (short)f2b(u0[j]);
                    tv[4 + j] = (short)f2b(u1[j]);
                }
                *(short8*)(At + (size_t)s * 8) = tv;
            }
        }
        __syncthreads();
#pragma unroll
        for (int ks = 0; ks < 2; ++ks) {
            short8 af[4], bf[4];
#pragma unroll
            for (int mt = 0; mt < 4; ++mt) {
                const int row = wr * 64 + mt * 16 + cl;
                const int slot = row * 8 + ((ks * 4 + quad) ^ (row & 7));
                af[mt] = *(const short8*)(At + slot * 8);
            }
#pragma unroll
            for (int nt = 0; nt < 4; ++nt) {
                const int row = wc * 64 + nt * 16 + cl;
                const int slot = row * 8 + ((ks * 4 + quad) ^ (row & 7));
                bf[nt] = *(const short8*)(Bt + slot * 8);
            }
#pragma unroll
            for (int mt = 0; mt < 4; ++mt)
#pragma unroll
                for (int nt = 0; nt < 4; ++nt)
                    acc[mt][nt] = __builtin_amdgcn_mfma_f32_16x16x32_bf16(af[mt], bf[nt], acc[mt][nt], 0, 0, 0);
        }
    }
    // Epilogue. C/D layout (m89-verified): col=lane&15, row=quad*4+reg.
    if (!isf_c) {
        // bf16 C: bounce through wave-private LDS quarter, full-line stores.
        __syncthreads();  // all waves done reading At/Bt
        uint16_t* const Ob = ((w & 2) ? Bt : At) + (w & 1) * 4096;  // 64x64
#pragma unroll
        for (int nt = 0; nt < 4; ++nt) {
            const int col = nt * 16 + cl;  // wave-local col
            const float bv = isf_bias ? ((const float*)biasv)[n0 + wc * 64 + col]
                                      : b2f(((const uint16_t*)biasv)[n0 + wc * 64 + col]);
#pragma unroll
            for (int mt = 0; mt < 4; ++mt)
#pragma unroll
                for (int r = 0; r < 4; ++r) {
                    const int row = mt * 16 + quad * 4 + r;  // wave-local row
                    Ob[row * 64 + (((col >> 3) ^ (row & 7)) & 7) * 8 + (col & 7)] =
                        f2b(acc[mt][nt][r] + bv);
                }
        }
#pragma unroll
        for (int g = 0; g < 8; ++g) {
            const int row = g * 8 + (lane >> 3);
            const int c = lane & 7;
            const short8 ov = *(const short8*)(Ob + row * 64 + ((c ^ (row & 7)) & 7) * 8);
            *(short8*)((uint16_t*)Cv + (size_t)(m0 + wr * 64 + row) * 512 + n0 + wc * 64 + c * 8) = ov;
        }
    } else {
#pragma unroll
        for (int nt = 0; nt < 4; ++nt) {
            const int col = n0 + wc * 64 + nt * 16 + cl;
            const float bv = isf_bias ? ((const float*)biasv)[col] : b2f(((const uint16_t*)biasv)[col]);
#pragma unroll
            for (int mt = 0; mt < 4; ++mt)
#pragma unroll
                for (int r = 0; r < 4; ++r) {
                    const int rowg = m0 + wr * 64 + mt * 16 + quad * 4 + r;
                    ((float*)Cv)[(size_t)rowg * 512 + col] = acc[mt][nt][r] + bv;
                }
        }
    }
}

// Grid (4,512,3): 6144 blocks. Bijective XCD remap (6144%8==0, chunk=768):
// nid=(id&7)*768+(id>>3); decompose nid with n-tile fastest. The 4 n-siblings
// of one A-tile are consecutive nid -> same XCD, ~simultaneous dispatch.
__global__ __launch_bounds__(256, 2) void k_gemm_proj(
    const void* qi, const void* ki, const void* vi,
    const uint16_t* wtq, const uint16_t* wtk, const uint16_t* wtv,
    const void* bq, const void* bk, const void* bv,
    uint16_t* cq, uint16_t* ck, uint16_t* cv, const int* flag) {
    const int isf = *flag;
    const int id = blockIdx.x + (blockIdx.y << 2) + (blockIdx.z << 11);
    const int nid = (id & 7) * 768 + (id >> 3);
    const int z = nid >> 11;
    const int y = (nid >> 2) & 511;   // m-tile
    const int x = nid & 3;            // n-tile (fast)
    const void* A = (z == 0) ? qi : (z == 1) ? ki : vi;
    const uint16_t* W = (z == 0) ? wtq : (z == 1) ? wtk : wtv;
    const void* B = (z == 0) ? bq : (z == 1) ? bk : bv;
    uint16_t* C = (z == 0) ? cq : (z == 1) ? ck : cv;
    gemm_dev<2>(A, 128, W, B, C, y * 128, x * 128, isf, isf, 0);  // C bf16
}

// Grid (4,512): 2048 blocks, chunk=256.
__global__ __launch_bounds__(256, 2) void k_gemm_out(
    const uint16_t* __restrict__ A, const uint16_t* __restrict__ Wt,
    const void* __restrict__ bias, void* __restrict__ C, const int* flag) {
    const int isf = *flag;
    const int id = blockIdx.x + (blockIdx.y << 2);
    const int nid = (id & 7) * 256 + (id >> 3);
    const int y = nid >> 2;
    const int x = nid & 3;
    gemm_dev<8>(A, 512, Wt, bias, C, y * 128, x * 128, 0, isf, isf);
}

// ---------------------------------------------------------------------------
// Attention v4 (unchanged -- measured good): block per (bn,head);
// 4 waves x 64 query rows; flash loop over 4 key-tiles of 64; K/V double-
// buffered with prefetch; in-register P via swapped QK^T + pi-permuted V.
// ---------------------------------------------------------------------------
__global__ __launch_bounds__(256, 2) void k_attn(const uint16_t* __restrict__ qws,
                                                 const uint16_t* __restrict__ kws,
                                                 const uint16_t* __restrict__ vws,
                                                 uint16_t* __restrict__ ows) {
    // uint16 element offsets into sm (32 KB total):
    //   Kb[buf]: buf*4096            (64 rows x 8 chunks x 8, chunk-XOR swizzled)
    //   Vt[buf]: 8192 + buf*4096     (64 dims x 64 key-slots, pi-permuted + swizzled)
    __shared__ __align__(16) uint16_t sm[16384];

    const int bx = blockIdx.x;
    const int bn = bx >> 3, h = bx & 7;
    const int tid = threadIdx.x;
    const int lane = tid & 63, w = tid >> 6;
    const int quad = lane >> 4, cl = lane & 15;
    const size_t base = (size_t)bn * 256 * 512 + h * 64;
    const int qbase = w * 64;

    // Q fragments (B-operand of swapped QK; same layout as A-frag):
    // lane holds Q[qbase+mt*16+cl][ks*32+quad*8+j]
    short8 qf[4][2];
#pragma unroll
    for (int mt = 0; mt < 4; ++mt)
#pragma unroll
        for (int ks = 0; ks < 2; ++ks)
            qf[mt][ks] = *(const short8*)(qws + base + (size_t)(qbase + mt * 16 + cl) * 512 + ks * 32 + quad * 8);

    f32x4 O[4][4];
    float lsum[4];
#pragma unroll
    for (int mt = 0; mt < 4; ++mt) {
#pragma unroll
        for (int nt = 0; nt < 4; ++nt) O[mt][nt] = (f32x4){0.f, 0.f, 0.f, 0.f};
        lsum[mt] = 0.f;
    }

    short8 vreg[2];
    // ---- prologue: stage tile 0 into buffer 0 ----
    {
#pragma unroll
        for (int i = 0; i < 2; ++i) {
            const int s = i * 256 + tid;
            const int row = s >> 3;
            const int gc = (s & 7) ^ (row & 7);
            __builtin_amdgcn_global_load_lds(AS1(kws + base + (size_t)row * 512 + gc * 8),
                                             AS3(sm + (i * 256 + w * 64) * 8), 16, 0, 0);
        }
#pragma unroll
        for (int i = 0; i < 2; ++i) {
            const int it = i * 256 + tid;
            const int key = it >> 3, db = (it & 7) * 8;
            vreg[i] = *(const short8*)(vws + base + (size_t)key * 512 + db);
        }
        // V write with pi-permuted key->slot map: slot chunk c=(key>>5)*4+((key>>2)&3),
        // elem j2=((key>>4)&1)*4+(key&3); chunk XOR-swizzled by fd per d-row.
#pragma unroll
        for (int i = 0; i < 2; ++i) {
            const int it = i * 256 + tid;
            const int key = it >> 3, db = (it & 7) * 8;
            const int c = ((key >> 5) & 1) * 4 + ((key >> 2) & 3);
            const int j2 = ((key >> 4) & 1) * 4 + (key & 3);
#pragma unroll
            for (int j = 0; j < 8; ++j) {
                const int d = db + j;
                const int fd = ((d >> 3) ^ d) & 7;
                sm[8192 + d * 64 + ((c ^ fd) & 7) * 8 + j2] = (uint16_t)vreg[i][j];
            }
        }
    }
    __syncthreads();

    int cur = 0;
#pragma unroll 1
    for (int kb = 0; kb < 4; ++kb) {
        const uint16_t* const Kc = sm + cur * 4096;
        const uint16_t* const Vc = sm + 8192 + cur * 4096;
        const int nb = cur ^ 1;

        // ---- issue next tile's loads (fly under this tile's compute) ----
        if (kb < 3) {
#pragma unroll
            for (int i = 0; i < 2; ++i) {
                const int s = i * 256 + tid;
                const int row = s >> 3;
                const int gc = (s & 7) ^ (row & 7);
                __builtin_amdgcn_global_load_lds(AS1(kws + base + (size_t)((kb + 1) * 64 + row) * 512 + gc * 8),
                                                 AS3(sm + nb * 4096 + (i * 256 + w * 64) * 8), 16, 0, 0);
            }
#pragma unroll
            for (int i = 0; i < 2; ++i) {
                const int it = i * 256 + tid;
                const int key = it >> 3, db = (it & 7) * 8;
                vreg[i] = *(const short8*)(vws + base + (size_t)((kb + 1) * 64 + key) * 512 + db);
            }
        }

        // ---- compute on current tile: two key-halves of 32 ----
#pragma unroll
        for (int hf = 0; hf < 2; ++hf) {
            // K fragments for this half: global nt = hf*2 + nt2
            short8 kf[2][2];
#pragma unroll
            for (int nt2 = 0; nt2 < 2; ++nt2)
#pragma unroll
                for (int ks = 0; ks < 2; ++ks) {
                    const int row = (hf * 2 + nt2) * 16 + cl;
                    const int slot = row * 8 + ((ks * 4 + quad) ^ (row & 7));
                    kf[nt2][ks] = *(const short8*)(Kc + slot * 8);
                }
            // V fragments for this half's PV step (chunk hf*4+quad, pi order)
            short8 vf[4];
#pragma unroll
            for (int nt = 0; nt < 4; ++nt) {
                const int d = nt * 16 + cl;
                const int fd = ((d >> 3) ^ d) & 7;
                vf[nt] = *(const short8*)(Vc + d * 64 + (((hf * 4 + quad) ^ fd) & 7) * 8);
            }
#pragma unroll
            for (int mt = 0; mt < 4; ++mt) {
                // swapped QK: S2[key][q], lane holds q=cl, key=(hf*2+nt2)*16+quad*4+r
                f32x4 S0 = (f32x4){0.f, 0.f, 0.f, 0.f};
                f32x4 S1 = (f32x4){0.f, 0.f, 0.f, 0.f};
#pragma unroll
                for (int ks = 0; ks < 2; ++ks) {
                    S0 = __builtin_amdgcn_mfma_f32_16x16x32_bf16(kf[0][ks], qf[mt][ks], S0, 0, 0, 0);
                    S1 = __builtin_amdgcn_mfma_f32_16x16x32_bf16(kf[1][ks], qf[mt][ks], S1, 0, 0, 0);
                }
                // exp + pack into the PV A-fragment (pi-matched: j>>2 -> nt2, j&3 -> r)
                short8 pf;
                float ls = 0.f;
#pragma unroll
                for (int r = 0; r < 4; ++r) {
                    const float pv = __expf(S0[r] * 0.125f);
                    ls += pv;
                    pf[r] = (short)f2b(pv);
                }
#pragma unroll
                for (int r = 0; r < 4; ++r) {
                    const float pv = __expf(S1[r] * 0.125f);
                    ls += pv;
                    pf[4 + r] = (short)f2b(pv);
                }
                lsum[mt] += ls;
#pragma unroll
                for (int nt = 0; nt < 4; ++nt)
                    O[mt][nt] = __builtin_amdgcn_mfma_f32_16x16x32_bf16(pf, vf[nt], O[mt][nt], 0, 0, 0);
            }
        }

        // ---- late half of V staging: pi-permuted ds_writes into next buffer ----
        if (kb < 3) {
#pragma unroll
            for (int i = 0; i < 2; ++i) {
                const int it = i * 256 + tid;
                const int key = it >> 3, db = (it & 7) * 8;
                const int c = ((key >> 5) & 1) * 4 + ((key >> 2) & 3);
                const int j2 = ((key >> 4) & 1) * 4 + (key & 3);
#pragma unroll
                for (int j = 0; j < 8; ++j) {
                    const int d = db + j;
                    const int fd = ((d >> 3) ^ d) & 7;
                    sm[8192 + nb * 4096 + d * 64 + ((c ^ fd) & 7) * 8 + j2] = (uint16_t)vreg[i][j];
                }
            }
        }
        __syncthreads();  // next tile fully staged; everyone done reading cur
        cur = nb;
    }

    // Row-sum: lane holds the partial for q=mt*16+cl over its quad's keys;
    // combine the 4 quads (lanes cl, cl+16, cl+32, cl+48).
    float linv[4];
#pragma unroll
    for (int mt = 0; mt < 4; ++mt) {
        float v = lsum[mt];
        v += __shfl_xor(v, 16, 64);
        v += __shfl_xor(v, 32, 64);
        linv[mt] = 1.0f / v;
    }

    // Epilogue: O layout is q=mt*16+quad*4+r, d=nt*16+cl. Normalizer for row
    // quad*4+r lives at lane cl=quad*4+r (any quad). Bounce normalized bf16 O
    // through the dead K/V LDS (chunk-XOR swizzled), then stores where one
    // instruction's 64 lanes cover 8 complete 128B row-slices.
    uint16_t* const Ob = sm + w * 4096;
#pragma unroll
    for (int mt = 0; mt < 4; ++mt) {
        float ln4[4];
#pragma unroll
        for (int r = 0; r < 4; ++r) ln4[r] = __shfl(linv[mt], quad * 4 + r, 64);
#pragma unroll
        for (int nt = 0; nt < 4; ++nt)
#pragma unroll
            for (int r = 0; r < 4; ++r) {
                const int row = mt * 16 + quad * 4 + r;
                const int col = nt * 16 + cl;
                Ob[row * 64 + ((((col >> 3) ^ (row & 7)) & 7) * 8 + (col & 7))] =
                    f2b(O[mt][nt][r] * ln4[r]);
            }
    }
    // lane -> (row = g*8 + lane>>3, chunk = lane&7): full 64B lines per inst.
#pragma unroll
    for (int g = 0; g < 8; ++g) {
        const int row = g * 8 + (lane >> 3);
        const int c = lane & 7;
        const short8 ov = *(const short8*)(Ob + row * 64 + ((c ^ (row & 7)) & 7) * 8);
        *(short8*)(ows + base + (size_t)(qbase + row) * 512 + c * 8) = ov;
    }
}

// ---------------------------------------------------------------------------
extern "C" void kernel_launch(void* const* d_in, const int* in_sizes, int n_in,
                              void* d_out, int out_size, void* d_ws, size_t ws_size,
                              hipStream_t stream) {
    uint16_t* ws = (uint16_t*)d_ws;

    int* flag = (int*)d_ws;                   // 4 bytes
    uint16_t* wt_q = ws + 256;                // 512x128 bf16
    uint16_t* wt_k = wt_q + 128 * 512;
    uint16_t* wt_v = wt_k + 128 * 512;
    uint16_t* wt_o = wt_v + 128 * 512;        // 512x512 bf16
    uint16_t* q_ws = wt_o + 512 * 512;        // 65536x512 bf16; also attn out
    const size_t QKV = (size_t)65536 * 512;
    uint16_t* k_ws = q_ws + QKV;
    uint16_t* v_ws = k_ws + QKV;
    // total ws use ~193 MiB

    k_detect<<<1, 64, 0, stream>>>((const uint16_t*)d_in[0], flag);
    k_transpose<<<dim3(1024, 4), 256, 0, stream>>>(d_in[3], d_in[5], d_in[7], d_in[9],
                                                   wt_q, wt_k, wt_v, wt_o, flag);
    k_gemm_proj<<<dim3(4, 512, 3), 256, 0, stream>>>(d_in[0], d_in[1], d_in[2],
                                                     wt_q, wt_k, wt_v,
                                                     d_in[4], d_in[6], d_in[8],
                                                     q_ws, k_ws, v_ws, flag);
    k_attn<<<dim3(2048), 256, 0, stream>>>(q_ws, k_ws, v_ws, q_ws);
    k_gemm_out<<<dim3(4, 512), 256, 0, stream>>>(q_ws, wt_o, d_in[10], d_out, flag);
}